// Round 7
// baseline (726.336 us; speedup 1.0000x reference)
//
#include <hip/hip_runtime.h>

// B=32, LV=196, LT=40, D=512, H=8, DH=64

typedef unsigned int u32;
typedef unsigned short u16;
typedef __attribute__((ext_vector_type(8))) short bf16x8;
typedef __attribute__((ext_vector_type(4))) float f32x4;

#define DEV __device__ __forceinline__

DEV u16 f2bf(float f) {
  u32 u = __builtin_bit_cast(u32, f);
  u = (u + 0x7FFFu + ((u >> 16) & 1u)) >> 16;
  return (u16)u;
}
DEV float bf2f(u16 h) { u32 u = ((u32)h) << 16; return __builtin_bit_cast(float, u); }
DEV u32 encf(float f) { u32 u = __builtin_bit_cast(u32, f); return (u & 0x80000000u) ? ~u : (u | 0x80000000u); }
DEV float decf2(u32 e) { u32 u = (e & 0x80000000u) ? (e & 0x7FFFFFFFu) : ~e; return __builtin_bit_cast(float, u); }

// ---------------- fused prep: plain casts + maxbuf zero ----------------
__global__ __launch_bounds__(256) void k_prep(const float* __restrict__ bef, const float* __restrict__ aft,
                                              const float* __restrict__ in_proj_w, const float* __restrict__ k_w,
                                              const float* __restrict__ q_w,
                                              u16* __restrict__ bef16, u16* __restrict__ aft16,
                                              u16* __restrict__ inproj16, u16* __restrict__ kw16,
                                              u16* __restrict__ qw16, uint4* __restrict__ maxbuf) {
  int i = blockIdx.x * blockDim.x + threadIdx.x; // 0 .. 1,067,007
  const float* src; u16* dst; int j;
  if (i < 401408) { src = bef; dst = bef16; j = i; }
  else if (i < 802816) { src = aft; dst = aft16; j = i - 401408; }
  else if (i < 901120) { src = in_proj_w; dst = inproj16; j = i - 802816; }
  else if (i < 933888) { src = k_w; dst = kw16; j = i - 901120; }
  else if (i < 966656) { src = q_w; dst = qw16; j = i - 933888; }
  else { maxbuf[i - 966656] = (uint4){0u, 0u, 0u, 0u}; return; }
  const float4* p = (const float4*)src + (size_t)j * 2;
  float4 a = p[0], b = p[1];
  u16 t[8] = {f2bf(a.x), f2bf(a.y), f2bf(a.z), f2bf(a.w),
              f2bf(b.x), f2bf(b.y), f2bf(b.z), f2bf(b.w)};
  *(uint4*)(dst + (size_t)j * 8) = *(uint4*)t;
}

// out[r*512+c] = bf16(in[c*instride+r]) for three weights (z selects; z=2 is conv1_w left half)
__global__ __launch_bounds__(256) void k_transpose3(const float* __restrict__ in0, u16* __restrict__ out0,
                                                    const float* __restrict__ in1, u16* __restrict__ out1,
                                                    const float* __restrict__ in2, u16* __restrict__ out2) {
  __shared__ float t[32][33];
  const float* in = blockIdx.z == 0 ? in0 : (blockIdx.z == 1 ? in1 : in2);
  u16* out = blockIdx.z == 0 ? out0 : (blockIdx.z == 1 ? out1 : out2);
  const int instride = blockIdx.z == 2 ? 1024 : 512;
  int bx = blockIdx.x, by = blockIdx.y;
  int tx = threadIdx.x & 31, ty = threadIdx.x >> 5;
  for (int i = ty; i < 32; i += 8) t[i][tx] = in[(size_t)(by * 32 + i) * instride + bx * 32 + tx];
  __syncthreads();
  for (int i = ty; i < 32; i += 8) out[(size_t)(bx * 32 + i) * 512 + by * 32 + tx] = f2bf(t[tx][i]);
}

// ---------------- sentbias -> biasqkv (blocks 0..31) + biasq (block 32) ----------------
// biasqkv[b,e] = (mean_t(sent*mask) @ conv1_w[:,512:]^T + conv1_b) @ in_proj_w^T
__global__ __launch_bounds__(256) void k_sentbias3(const float* __restrict__ sent, const float* __restrict__ masks,
                                                   const float* __restrict__ conv1_w, const float* __restrict__ conv1_b,
                                                   const float* __restrict__ in_proj_w,
                                                   const float* __restrict__ q_w, const float* __restrict__ conv2_b,
                                                   const float* __restrict__ q_b,
                                                   float* __restrict__ biasqkv, float* __restrict__ biasq) {
  int b = blockIdx.x, tid = threadIdx.x;
  if (b == 32) {
    for (int j = tid; j < 512; j += 256) {
      const float* wr = q_w + (size_t)j * 512;
      float acc = q_b[j];
#pragma unroll 8
      for (int d = 0; d < 512; ++d) acc += wr[d] * conv2_b[d];
      biasq[j] = acc;
    }
    return;
  }
  __shared__ float sm[512];
  __shared__ float bb[512];
  for (int d = tid; d < 512; d += 256) {
    float s = 0.f;
#pragma unroll 8
    for (int t = 0; t < 40; ++t) s += sent[(size_t)b * 40 * 512 + (size_t)t * 512 + d] * masks[b * 40 + t];
    sm[d] = s * (1.0f / 40.0f);
  }
  __syncthreads();
  for (int o = tid; o < 512; o += 256) {
    const float* wr = conv1_w + (size_t)o * 1024 + 512;
    float acc = conv1_b[o];
#pragma unroll 8
    for (int c = 0; c < 512; ++c) acc += sm[c] * wr[c];
    bb[o] = acc;
  }
  __syncthreads();
  for (int e = tid; e < 1536; e += 256) {
    const float* wr = in_proj_w + (size_t)e * 512;
    float acc = 0.f;
#pragma unroll 8
    for (int o = 0; o < 512; ++o) acc += bb[o] * wr[o];
    biasqkv[b * 1536 + e] = acc;
  }
}

// ---------------- GEMM: C = X(Mx512) @ W(Nx512)^T, 128x64 tile ----------------
// Software-pipelined roundtrip staging: prologue load; per chunk
// sync -> LDS-store -> sync -> load next -> MFMA (next-chunk latency hides
// under MFMAs). Straight coalesced loads; XOR store slot cg^(r&7) on unpadded
// 64-elem rows; MFMA reads use matching XOR -> 0 bank conflicts.
// Wave w owns rows [w*32, w*32+32): acc[2][4]. 24KB LDS -> high occupancy.
// biasMode: 0 none, 1 bias[col], 2 bias[(row/196)*bstr + col].
// Dual sets: blockIdx.y >= ySplit selects set 1; set0 guarded by xLim0.
__global__ __launch_bounds__(256) void k_gemm(
    const u16* __restrict__ X0, const u16* __restrict__ W0, u16* __restrict__ out0, const float* __restrict__ bias0,
    int N0, int bm0, int bstr0, int xLim0,
    const u16* __restrict__ X1, const u16* __restrict__ W1, u16* __restrict__ out1, const float* __restrict__ bias1,
    int N1, int bm1, int bstr1, int ySplit) {
  const int sel = (int)blockIdx.y >= ySplit;
  if (!sel && (int)blockIdx.x >= xLim0) return;
  const u16* X = sel ? X1 : X0;
  const u16* W = sel ? W1 : W0;
  u16* out = sel ? out1 : out0;
  const float* bias = sel ? bias1 : bias0;
  const int N = sel ? N1 : N0, bm = sel ? bm1 : bm0, bstr = sel ? bstr1 : bstr0;
  const int tileM = blockIdx.x * 128, tileN = (sel ? blockIdx.y - ySplit : blockIdx.y) * 64;
  __shared__ u16 As[128 * 64]; // 16 KB
  __shared__ u16 Bs[64 * 64];  // 8 KB
  const int tid = threadIdx.x;
  const int wave = tid >> 6, lane = tid & 63, quad = lane >> 4, l15 = lane & 15;
  const f32x4 z = {0.f, 0.f, 0.f, 0.f};
  f32x4 acc[2][4];
#pragma unroll
  for (int s = 0; s < 2; ++s)
#pragma unroll
    for (int t = 0; t < 4; ++t) acc[s][t] = z;
  const u16* xb = X + (size_t)tileM * 512;
  const u16* wb = W + (size_t)tileN * 512;
  uint4 regs[6];
#pragma unroll
  for (int j = 0; j < 6; ++j) {
    int idx = tid + j * 256, r = idx >> 3, cg = idx & 7;
    const u16* src = (r < 128) ? (xb + (size_t)r * 512) : (wb + (size_t)(r - 128) * 512);
    regs[j] = *(const uint4*)(src + cg * 8);
  }
  for (int kc = 0; kc < 512; kc += 64) {
    __syncthreads();
#pragma unroll
    for (int j = 0; j < 6; ++j) {
      int idx = tid + j * 256, r = idx >> 3, cg = idx & 7;
      int slot = (cg ^ (r & 7)) * 8;
      if (r < 128) *(uint4*)&As[r * 64 + slot] = regs[j];
      else *(uint4*)&Bs[(r - 128) * 64 + slot] = regs[j];
    }
    __syncthreads();
    if (kc < 448) {
#pragma unroll
      for (int j = 0; j < 6; ++j) {
        int idx = tid + j * 256, r = idx >> 3, cg = idx & 7;
        const u16* src = (r < 128) ? (xb + (size_t)r * 512) : (wb + (size_t)(r - 128) * 512);
        regs[j] = *(const uint4*)(src + kc + 64 + cg * 8);
      }
    }
#pragma unroll
    for (int kk = 0; kk < 64; kk += 32) {
      const int swz = ((((kk >> 3) + quad) ^ (l15 & 7)) * 8);
      bf16x8 af0 = *(const bf16x8*)&As[(wave * 32 + l15) * 64 + swz];
      bf16x8 af1 = *(const bf16x8*)&As[(wave * 32 + 16 + l15) * 64 + swz];
#pragma unroll
      for (int t = 0; t < 4; ++t) {
        bf16x8 bfr = *(const bf16x8*)&Bs[(t * 16 + l15) * 64 + swz];
        acc[0][t] = __builtin_amdgcn_mfma_f32_16x16x32_bf16(af0, bfr, acc[0][t], 0, 0, 0);
        acc[1][t] = __builtin_amdgcn_mfma_f32_16x16x32_bf16(af1, bfr, acc[1][t], 0, 0, 0);
      }
    }
  }
#pragma unroll
  for (int s = 0; s < 2; ++s) {
    int row0 = tileM + wave * 32 + s * 16 + quad * 4;
#pragma unroll
    for (int t = 0; t < 4; ++t) {
      int col = tileN + t * 16 + l15;
      float bv = (bm == 1) ? bias[col] : 0.0f;
#pragma unroll
      for (int r = 0; r < 4; ++r) {
        int row = row0 + r;
        float v = acc[s][t][r] + bv;
        if (bm == 2) v += bias[(row / 196) * bstr + col];
        out[(size_t)row * N + col] = f2bf(v);
      }
    }
  }
}

// ---------------- MFMA attention: one block (4 waves) per (b,h) ----------------
__global__ __launch_bounds__(256, 1) void k_attn2(const u16* __restrict__ qkv, u16* __restrict__ o_out) {
  const int b = blockIdx.x >> 3, h = blockIdx.x & 7;
  __shared__ u16 Ks[208 * 72];
  __shared__ u16 Vt[64 * 232];
  __shared__ u16 Ps[4][16 * 232];
  const int tid = threadIdx.x;
  const int wave = tid >> 6, lane = tid & 63, quad = lane >> 4, l15 = lane & 15;
  const size_t base = (size_t)b * 196 * 1536 + (size_t)h * 64;

  for (int i = tid; i < 64 * 232 / 4; i += 256) ((unsigned long long*)Vt)[i] = 0ULL;
  for (int i = tid; i < 4 * 16 * 24; i += 256) {
    int w = i / 384, rem = i - w * 384;
    int r = rem / 24, c = rem - r * 24;
    Ps[w][r * 232 + 208 + c] = 0;
  }
  __syncthreads();

  for (int idx = tid; idx < 208 * 8; idx += 256) {
    int r = idx >> 3, c = (idx & 7) * 8;
    uint4 v = {0, 0, 0, 0};
    if (r < 196) v = *(const uint4*)&qkv[base + 512 + (size_t)r * 1536 + c];
    *(uint4*)&Ks[r * 72 + c] = v;
  }
  for (int idx = tid; idx < 196 * 8; idx += 256) {
    int p = idx >> 3, f0 = (idx & 7) * 8;
    uint4 v = *(const uint4*)&qkv[base + 1024 + (size_t)p * 1536 + f0];
    u16 t[8]; *(uint4*)t = v;
#pragma unroll
    for (int j = 0; j < 8; ++j) Vt[(f0 + j) * 232 + p] = t[j];
  }
  bf16x8 qz = {0, 0, 0, 0, 0, 0, 0, 0};
  bf16x8 qf[4][2];
#pragma unroll
  for (int i = 0; i < 4; ++i) {
    int s = wave + i * 4;
    int row = s * 16 + l15;
#pragma unroll
    for (int c = 0; c < 2; ++c) {
      bf16x8 v = qz;
      if (s < 13 && row < 196)
        v = *(const bf16x8*)&qkv[base + (size_t)row * 1536 + c * 32 + quad * 8];
      qf[i][c] = v;
    }
  }
  __syncthreads();

  const f32x4 z = {0.f, 0.f, 0.f, 0.f};
  for (int i = 0; i < 4; ++i) {
    int s = wave + i * 4;
    if (s >= 13) break;
    f32x4 acc[13];
#pragma unroll
    for (int nt = 0; nt < 13; ++nt) acc[nt] = z;
#pragma unroll
    for (int c = 0; c < 2; ++c) {
      bf16x8 a = qf[i][c];
#pragma unroll
      for (int nt = 0; nt < 13; ++nt) {
        bf16x8 bfr = *(const bf16x8*)&Ks[(nt * 16 + l15) * 72 + c * 32 + quad * 8];
        acc[nt] = __builtin_amdgcn_mfma_f32_16x16x32_bf16(a, bfr, acc[nt], 0, 0, 0);
      }
    }
#pragma unroll
    for (int r = 0; r < 4; ++r) {
      float m = -3e38f;
#pragma unroll
      for (int nt = 0; nt < 13; ++nt) {
        float sv = acc[nt][r] * 0.125f;
        acc[nt][r] = sv;
        if (nt < 12 || l15 < 4) m = fmaxf(m, sv);
      }
#pragma unroll
      for (int off = 1; off < 16; off <<= 1) m = fmaxf(m, __shfl_xor(m, off));
      float ssum = 0.f;
#pragma unroll
      for (int nt = 0; nt < 13; ++nt) {
        float p = (nt < 12 || l15 < 4) ? __expf(acc[nt][r] - m) : 0.f;
        acc[nt][r] = p;
        ssum += p;
      }
#pragma unroll
      for (int off = 1; off < 16; off <<= 1) ssum += __shfl_xor(ssum, off);
      float is = 1.0f / ssum;
      int row = quad * 4 + r;
#pragma unroll
      for (int nt = 0; nt < 13; ++nt) {
        float v = acc[nt][r] * is;
        float vx = __shfl_xor(v, 1);
        if ((l15 & 1) == 0) {
          u32 pk = (u32)f2bf(v) | ((u32)f2bf(vx) << 16);
          *(u32*)&Ps[wave][row * 232 + nt * 16 + l15] = pk;
        }
      }
    }
    f32x4 oacc[4] = {z, z, z, z};
#pragma unroll
    for (int kc = 0; kc < 7; ++kc) {
      bf16x8 a = *(const bf16x8*)&Ps[wave][l15 * 232 + kc * 32 + quad * 8];
#pragma unroll
      for (int nt = 0; nt < 4; ++nt) {
        bf16x8 bfr = *(const bf16x8*)&Vt[(nt * 16 + l15) * 232 + kc * 32 + quad * 8];
        oacc[nt] = __builtin_amdgcn_mfma_f32_16x16x32_bf16(a, bfr, oacc[nt], 0, 0, 0);
      }
    }
#pragma unroll
    for (int nt = 0; nt < 4; ++nt) {
#pragma unroll
      for (int r = 0; r < 4; ++r) {
        int row = s * 16 + quad * 4 + r;
        if (row < 196)
          o_out[((size_t)b * 196 + row) * 512 + h * 64 + nt * 16 + l15] = f2bf(oacc[nt][r]);
      }
    }
  }
}

// ---------------- logits: QL(6272x512) @ KL_b(196x512)^T with fused row/col max ----------------
// 1D grid 1568, XCD-swizzled b; 128 rows x 208 cols; pipelined roundtrip +
// XOR store slot (0 conflicts).
__global__ __launch_bounds__(256) void k_logits6(const u16* __restrict__ QL, const u16* __restrict__ KL,
                                                 u32* __restrict__ rowmax, u32* __restrict__ colmax) {
  const int id = blockIdx.x;
  const int b = (id & 7) * 4 + ((id >> 3) & 3);
  const int row0 = (id >> 5) * 128;
  __shared__ u16 As[128 * 64];        // 16 KB
  __shared__ u16 Bs[208 * 64];        // 26 KB
  __shared__ float colred[2][4 * 208];// 6.5 KB
  const int tid = threadIdx.x;
  const int wave = tid >> 6, lane = tid & 63, quad = lane >> 4, l15 = lane & 15;
  const int a0 = row0 / 196;
  const int lsplit = (a0 + 1) * 196 - row0;
  const f32x4 z = {0.f, 0.f, 0.f, 0.f};
  f32x4 acc[2][13];
#pragma unroll
  for (int s = 0; s < 2; ++s)
#pragma unroll
    for (int nt = 0; nt < 13; ++nt) acc[s][nt] = z;
  const u16* qbase = QL + (size_t)row0 * 512;
  const u16* kbase = KL + (size_t)b * 196 * 512;

  uint4 qreg[4], kreg[7];
#pragma unroll
  for (int i = 0; i < 4; ++i) {
    int idx = tid + i * 256, r = idx >> 3, cg = idx & 7;
    qreg[i] = *(const uint4*)(qbase + (size_t)r * 512 + cg * 8);
  }
#pragma unroll
  for (int i = 0; i < 7; ++i) {
    int idx = tid + i * 256, r = idx >> 3, cg = idx & 7;
    uint4 v = {0, 0, 0, 0};
    if (idx < 1664 && r < 196) v = *(const uint4*)(kbase + (size_t)r * 512 + cg * 8);
    kreg[i] = v;
  }
  for (int kc = 0; kc < 512; kc += 64) {
    __syncthreads();
#pragma unroll
    for (int i = 0; i < 4; ++i) {
      int idx = tid + i * 256, r = idx >> 3, cg = idx & 7;
      *(uint4*)&As[r * 64 + ((cg ^ (r & 7)) * 8)] = qreg[i];
    }
#pragma unroll
    for (int i = 0; i < 7; ++i) {
      int idx = tid + i * 256;
      if (idx < 1664) {
        int r = idx >> 3, cg = idx & 7;
        *(uint4*)&Bs[r * 64 + ((cg ^ (r & 7)) * 8)] = kreg[i];
      }
    }
    __syncthreads();
    if (kc < 448) {
#pragma unroll
      for (int i = 0; i < 4; ++i) {
        int idx = tid + i * 256, r = idx >> 3, cg = idx & 7;
        qreg[i] = *(const uint4*)(qbase + (size_t)r * 512 + kc + 64 + cg * 8);
      }
#pragma unroll
      for (int i = 0; i < 7; ++i) {
        int idx = tid + i * 256, r = idx >> 3, cg = idx & 7;
        uint4 v = {0, 0, 0, 0};
        if (idx < 1664 && r < 196) v = *(const uint4*)(kbase + (size_t)r * 512 + kc + 64 + cg * 8);
        kreg[i] = v;
      }
    }
#pragma unroll
    for (int kk = 0; kk < 64; kk += 32) {
      const int swz = ((((kk >> 3) + quad) ^ (l15 & 7)) * 8);
      bf16x8 af0 = *(const bf16x8*)&As[(wave * 16 + l15) * 64 + swz];
      bf16x8 af1 = *(const bf16x8*)&As[((wave + 4) * 16 + l15) * 64 + swz];
#pragma unroll
      for (int nt = 0; nt < 13; ++nt) {
        bf16x8 bfr = *(const bf16x8*)&Bs[(nt * 16 + l15) * 64 + swz];
        acc[0][nt] = __builtin_amdgcn_mfma_f32_16x16x32_bf16(af0, bfr, acc[0][nt], 0, 0, 0);
        acc[1][nt] = __builtin_amdgcn_mfma_f32_16x16x32_bf16(af1, bfr, acc[1][nt], 0, 0, 0);
      }
    }
  }
  // ---- rowmax (masked cols >=196; keyed atomic per row) ----
#pragma unroll
  for (int s = 0; s < 2; ++s) {
#pragma unroll
    for (int r = 0; r < 4; ++r) {
      float m = -3e38f;
#pragma unroll
      for (int nt = 0; nt < 13; ++nt)
        if (nt < 12 || l15 < 4) m = fmaxf(m, acc[s][nt][r]);
#pragma unroll
      for (int off = 8; off > 0; off >>= 1) m = fmaxf(m, __shfl_xor(m, off, 16));
      if (l15 == 0) {
        int lr = (wave + s * 4) * 16 + quad * 4 + r;
        int aa = a0, ll = row0 - a0 * 196 + lr;
        if (ll >= 196) { aa += 1; ll -= 196; }
        atomicMax(&rowmax[((size_t)aa * 32 + b) * 196 + ll], encf(m));
      }
    }
  }
  // ---- colmax: segment rows by a before cross-quad shuffles ----
#pragma unroll
  for (int nt = 0; nt < 13; ++nt) {
    float cm0 = -3e38f, cm1 = -3e38f;
#pragma unroll
    for (int s = 0; s < 2; ++s)
#pragma unroll
      for (int r = 0; r < 4; ++r) {
        int lr = (wave + s * 4) * 16 + quad * 4 + r;
        float v = acc[s][nt][r];
        if (lr < lsplit) cm0 = fmaxf(cm0, v); else cm1 = fmaxf(cm1, v);
      }
    cm0 = fmaxf(cm0, __shfl_xor(cm0, 16)); cm0 = fmaxf(cm0, __shfl_xor(cm0, 32));
    cm1 = fmaxf(cm1, __shfl_xor(cm1, 16)); cm1 = fmaxf(cm1, __shfl_xor(cm1, 32));
    if (quad == 0) {
      colred[0][wave * 208 + nt * 16 + l15] = cm0;
      colred[1][wave * 208 + nt * 16 + l15] = cm1;
    }
  }
  __syncthreads();
  for (int c = tid; c < 196; c += 256) {
    float m0 = fmaxf(fmaxf(colred[0][c], colred[0][208 + c]), fmaxf(colred[0][416 + c], colred[0][624 + c]));
    atomicMax(&colmax[((size_t)a0 * 32 + b) * 196 + c], encf(m0));
    if (lsplit < 128) {
      float m1 = fmaxf(fmaxf(colred[1][c], colred[1][208 + c]), fmaxf(colred[1][416 + c], colred[1][624 + c]));
      atomicMax(&colmax[((size_t)(a0 + 1) * 32 + b) * 196 + c], encf(m1));
    }
  }
}

// ---------------- final: S matrix + symmetric cross-entropy ----------------
__global__ __launch_bounds__(1024) void k_final(const u32* __restrict__ maxbuf,
                                                const float* __restrict__ logit_scale, float* __restrict__ out) {
  __shared__ float S[1024];
  __shared__ float terms[64];
  int tid = threadIdx.x;
  float sc = 0.5f * __expf(logit_scale[0]);
  const uint4* rp = (const uint4*)(maxbuf + (size_t)tid * 196);
  const uint4* cp = (const uint4*)(maxbuf + 200704 + (size_t)tid * 196);
  float s = 0.f;
#pragma unroll 7
  for (int i = 0; i < 49; ++i) {
    uint4 v = rp[i]; s += decf2(v.x) + decf2(v.y) + decf2(v.z) + decf2(v.w);
    uint4 w = cp[i]; s += decf2(w.x) + decf2(w.y) + decf2(w.z) + decf2(w.w);
  }
  S[tid] = sc * s * (1.0f / 196.0f);
  __syncthreads();
  if (tid < 64) {
    int aa = tid & 31;
    bool rowMode = tid < 32;
    float mx = -3e38f;
    for (int j = 0; j < 32; ++j) {
      float v = rowMode ? S[aa * 32 + j] : S[j * 32 + aa];
      mx = fmaxf(mx, v);
    }
    float se = 0.f;
    for (int j = 0; j < 32; ++j) {
      float v = rowMode ? S[aa * 32 + j] : S[j * 32 + aa];
      se += __expf(v - mx);
    }
    terms[tid] = S[aa * 33] - (mx + logf(se));
  }
  __syncthreads();
  if (tid == 0) {
    float s2 = 0.f;
    for (int i = 0; i < 64; ++i) s2 += terms[i];
    out[0] = -s2 * (1.0f / 64.0f);
  }
}

// ---------------- host ----------------
extern "C" void kernel_launch(void* const* d_in, const int* in_sizes, int n_in,
                              void* d_out, int out_size, void* d_ws, size_t ws_size,
                              hipStream_t stream) {
  const float* bef       = (const float*)d_in[0];
  const float* sent      = (const float*)d_in[1];
  const float* aft       = (const float*)d_in[2];
  const float* masks     = (const float*)d_in[3];
  const float* conv1_w   = (const float*)d_in[4];
  const float* conv1_b   = (const float*)d_in[5];
  const float* in_proj_w = (const float*)d_in[6];
  const float* out_proj_w= (const float*)d_in[7];
  const float* conv2_w   = (const float*)d_in[8];
  const float* conv2_b   = (const float*)d_in[9];
  const float* q_w       = (const float*)d_in[10];
  const float* q_b       = (const float*)d_in[11];
  const float* k_w       = (const float*)d_in[12];
  const float* k_b       = (const float*)d_in[13];
  const float* logit_scale = (const float*)d_in[14];
  float* out = (float*)d_out;

  char* ws = (char*)d_ws;
  size_t off = 0;
  auto alloc = [&](size_t bytes) -> char* {
    char* p = ws + off;
    off += (bytes + 255) & ~(size_t)255;
    return p;
  };
  const size_t MROWS = 32 * 196; // 6272
  u16* bef16    = (u16*)alloc(MROWS * 512 * 2);
  u16* aft16    = (u16*)alloc(MROWS * 512 * 2);
  u16* inproj16 = (u16*)alloc(1536 * 512 * 2);
  u16* kw16     = (u16*)alloc(512 * 512 * 2);
  u16* qw16     = (u16*)alloc(512 * 512 * 2);
  u16* wcT16    = (u16*)alloc(512 * 512 * 2);
  u16* woT16    = (u16*)alloc(512 * 512 * 2);
  u16* w1aT16   = (u16*)alloc(512 * 512 * 2);
  u16* wt16     = (u16*)alloc(512 * 512 * 2);
  u16* wcomb16  = (u16*)alloc(512 * 512 * 2);
  u16* weff16   = (u16*)alloc(1536 * 512 * 2);
  float* biasq  = (float*)alloc(512 * 4);
  float* biasqkv= (float*)alloc(32 * 1536 * 4);
  u16* qkv16    = (u16*)alloc(MROWS * 1536 * 2);
  u16* oattn16  = (u16*)alloc(MROWS * 512 * 2);
  u16* QL16     = (u16*)alloc(MROWS * 512 * 2);
  u16* KL16     = (u16*)alloc(MROWS * 512 * 2);
  u32* maxbuf   = (u32*)alloc(2 * 32 * 32 * 196 * 4); // rowmax | colmax
  u32* rowmax   = maxbuf;
  u32* colmax   = maxbuf + 32 * 32 * 196;

  // casts + maxbuf zero (1,067,008 items = 4168 blocks exactly)
  k_prep<<<4168, 256, 0, stream>>>(bef, aft, in_proj_w, k_w, q_w,
                                   bef16, aft16, inproj16, kw16, qw16, (uint4*)maxbuf);
  k_transpose3<<<dim3(16, 16, 3), 256, 0, stream>>>(conv2_w, wcT16, out_proj_w, woT16, conv1_w, w1aT16);
  k_sentbias3<<<33, 256, 0, stream>>>(sent, masks, conv1_w, conv1_b, in_proj_w,
                                      q_w, conv2_b, q_b, biasqkv, biasq);
  // merged: y<8 -> Wt = Wq @ Wc (x<4) ; y>=8 -> Weff = Winproj @ W1a (x<12)
  k_gemm<<<dim3(12, 16), 256, 0, stream>>>(qw16, wcT16, wt16, nullptr, 512, 0, 0, 4,
                                           inproj16, w1aT16, weff16, nullptr, 512, 0, 0, 8);
  // Wcomb = Wt @ Wo
  k_gemm<<<dim3(4, 8), 256, 0, stream>>>(wt16, woT16, wcomb16, nullptr, 512, 0, 0, 4,
                                         wt16, woT16, wcomb16, nullptr, 512, 0, 0, 99);
  // qkv = bef @ Weff^T + biasqkv[b]  (v1 folded away)
  k_gemm<<<dim3(49, 24), 256, 0, stream>>>(bef16, weff16, qkv16, biasqkv, 1536, 2, 1536, 49,
                                           bef16, weff16, qkv16, biasqkv, 1536, 2, 1536, 99);
  // attention (MFMA)
  k_attn2<<<256, 256, 0, stream>>>(qkv16, oattn16);
  // merged: y<8 -> QL = o_attn @ Wcomb^T + biasq ; y>=8 -> KL = aft @ k_w^T + k_b
  k_gemm<<<dim3(49, 16), 256, 0, stream>>>(oattn16, wcomb16, QL16, biasq, 512, 1, 0, 49,
                                           aft16, kw16, KL16, k_b, 512, 1, 0, 8);
  // logits reductions
  k_logits6<<<1568, 256, 0, stream>>>(QL16, KL16, rowmax, colmax);
  // final loss
  k_final<<<1, 1024, 0, stream>>>(maxbuf, logit_scale, out);
}

// Round 8
// 532.135 us; speedup vs baseline: 1.3649x; 1.3649x over previous
//
#include <hip/hip_runtime.h>

// B=32, LV=196, LT=40, D=512, H=8, DH=64

typedef unsigned int u32;
typedef unsigned short u16;
typedef __attribute__((ext_vector_type(8))) short bf16x8;
typedef __attribute__((ext_vector_type(4))) float f32x4;

#define DEV __device__ __forceinline__

DEV u16 f2bf(float f) {
  u32 u = __builtin_bit_cast(u32, f);
  u = (u + 0x7FFFu + ((u >> 16) & 1u)) >> 16;
  return (u16)u;
}
DEV float bf2f(u16 h) { u32 u = ((u32)h) << 16; return __builtin_bit_cast(float, u); }
DEV u32 encf(float f) { u32 u = __builtin_bit_cast(u32, f); return (u & 0x80000000u) ? ~u : (u | 0x80000000u); }
DEV float decf2(u32 e) { u32 u = (e & 0x80000000u) ? (e & 0x7FFFFFFFu) : ~e; return __builtin_bit_cast(float, u); }

// ---------------- fused prep: plain casts + maxbuf zero ----------------
__global__ __launch_bounds__(256) void k_prep(const float* __restrict__ bef, const float* __restrict__ aft,
                                              const float* __restrict__ in_proj_w, const float* __restrict__ k_w,
                                              const float* __restrict__ q_w,
                                              u16* __restrict__ bef16, u16* __restrict__ aft16,
                                              u16* __restrict__ inproj16, u16* __restrict__ kw16,
                                              u16* __restrict__ qw16, uint4* __restrict__ maxbuf) {
  int i = blockIdx.x * blockDim.x + threadIdx.x; // 0 .. 1,067,007
  const float* src; u16* dst; int j;
  if (i < 401408) { src = bef; dst = bef16; j = i; }
  else if (i < 802816) { src = aft; dst = aft16; j = i - 401408; }
  else if (i < 901120) { src = in_proj_w; dst = inproj16; j = i - 802816; }
  else if (i < 933888) { src = k_w; dst = kw16; j = i - 901120; }
  else if (i < 966656) { src = q_w; dst = qw16; j = i - 933888; }
  else { maxbuf[i - 966656] = (uint4){0u, 0u, 0u, 0u}; return; }
  const float4* p = (const float4*)src + (size_t)j * 2;
  float4 a = p[0], b = p[1];
  u16 t[8] = {f2bf(a.x), f2bf(a.y), f2bf(a.z), f2bf(a.w),
              f2bf(b.x), f2bf(b.y), f2bf(b.z), f2bf(b.w)};
  *(uint4*)(dst + (size_t)j * 8) = *(uint4*)t;
}

// out[r*512+c] = bf16(in[c*instride+r]) for three weights (z selects; z=2 is conv1_w left half)
__global__ __launch_bounds__(256) void k_transpose3(const float* __restrict__ in0, u16* __restrict__ out0,
                                                    const float* __restrict__ in1, u16* __restrict__ out1,
                                                    const float* __restrict__ in2, u16* __restrict__ out2) {
  __shared__ float t[32][33];
  const float* in = blockIdx.z == 0 ? in0 : (blockIdx.z == 1 ? in1 : in2);
  u16* out = blockIdx.z == 0 ? out0 : (blockIdx.z == 1 ? out1 : out2);
  const int instride = blockIdx.z == 2 ? 1024 : 512;
  int bx = blockIdx.x, by = blockIdx.y;
  int tx = threadIdx.x & 31, ty = threadIdx.x >> 5;
  for (int i = ty; i < 32; i += 8) t[i][tx] = in[(size_t)(by * 32 + i) * instride + bx * 32 + tx];
  __syncthreads();
  for (int i = ty; i < 32; i += 8) out[(size_t)(bx * 32 + i) * 512 + by * 32 + tx] = f2bf(t[tx][i]);
}

// ---------------- sentbias -> biasqkv (blocks 0..31) + biasq (block 32) ----------------
__global__ __launch_bounds__(256) void k_sentbias3(const float* __restrict__ sent, const float* __restrict__ masks,
                                                   const float* __restrict__ conv1_w, const float* __restrict__ conv1_b,
                                                   const float* __restrict__ in_proj_w,
                                                   const float* __restrict__ q_w, const float* __restrict__ conv2_b,
                                                   const float* __restrict__ q_b,
                                                   float* __restrict__ biasqkv, float* __restrict__ biasq) {
  int b = blockIdx.x, tid = threadIdx.x;
  if (b == 32) {
    for (int j = tid; j < 512; j += 256) {
      const float* wr = q_w + (size_t)j * 512;
      float acc = q_b[j];
#pragma unroll 8
      for (int d = 0; d < 512; ++d) acc += wr[d] * conv2_b[d];
      biasq[j] = acc;
    }
    return;
  }
  __shared__ float sm[512];
  __shared__ float bb[512];
  for (int d = tid; d < 512; d += 256) {
    float s = 0.f;
#pragma unroll 8
    for (int t = 0; t < 40; ++t) s += sent[(size_t)b * 40 * 512 + (size_t)t * 512 + d] * masks[b * 40 + t];
    sm[d] = s * (1.0f / 40.0f);
  }
  __syncthreads();
  for (int o = tid; o < 512; o += 256) {
    const float* wr = conv1_w + (size_t)o * 1024 + 512;
    float acc = conv1_b[o];
#pragma unroll 8
    for (int c = 0; c < 512; ++c) acc += sm[c] * wr[c];
    bb[o] = acc;
  }
  __syncthreads();
  for (int e = tid; e < 1536; e += 256) {
    const float* wr = in_proj_w + (size_t)e * 512;
    float acc = 0.f;
#pragma unroll 8
    for (int o = 0; o < 512; ++o) acc += bb[o] * wr[o];
    biasqkv[b * 1536 + e] = acc;
  }
}

// ---------------- GEMM: C = X(Mx512) @ W(Nx512)^T, 64x64 tile (R3 engine) ----------------
// Padded LDS (stride 72), loads at loop top (scheduler pipelines across the
// barrier). 68 VGPR -> high occupancy; measured-best structure (R2/R3).
// biasMode: 0 none, 1 bias[col], 2 bias[(row/196)*bstr + col].
// Dual sets: blockIdx.y >= ySplit -> set 1; set0 guarded by xLim0 (block-uniform).
__global__ __launch_bounds__(256) void k_gemm(
    const u16* __restrict__ X0, const u16* __restrict__ W0, u16* __restrict__ out0, const float* __restrict__ bias0,
    int N0, int bm0, int bstr0, int xLim0,
    const u16* __restrict__ X1, const u16* __restrict__ W1, u16* __restrict__ out1, const float* __restrict__ bias1,
    int N1, int bm1, int bstr1, int ySplit) {
  const int sel = (int)blockIdx.y >= ySplit;
  if (!sel && (int)blockIdx.x >= xLim0) return;
  const u16* X = sel ? X1 : X0;
  const u16* W = sel ? W1 : W0;
  u16* out = sel ? out1 : out0;
  const float* bias = sel ? bias1 : bias0;
  const int N = sel ? N1 : N0, bm = sel ? bm1 : bm0, bstr = sel ? bstr1 : bstr0;
  const int tileM = blockIdx.x * 64, tileN = (sel ? blockIdx.y - ySplit : blockIdx.y) * 64;
  const int K = 512;
  __shared__ u16 Xl[64 * 72];
  __shared__ u16 Wl[64 * 72];
  int tid = threadIdx.x;
  int wave = tid >> 6, lane = tid & 63, quad = lane >> 4, l15 = lane & 15;
  f32x4 z = {0.f, 0.f, 0.f, 0.f};
  f32x4 acc[4] = {z, z, z, z};
  int srow = tid >> 2;
  int sk = (tid & 3) * 16;
  const u16* gx = X + (size_t)(tileM + srow) * K + sk;
  const u16* gw = W + (size_t)(tileN + srow) * K + sk;
  u16* lx = &Xl[srow * 72 + sk];
  u16* lw = &Wl[srow * 72 + sk];
  for (int kc = 0; kc < K; kc += 64) {
    uint4 x0 = *(const uint4*)(gx + kc);
    uint4 x1 = *(const uint4*)(gx + kc + 8);
    uint4 w0 = *(const uint4*)(gw + kc);
    uint4 w1 = *(const uint4*)(gw + kc + 8);
    __syncthreads();
    *(uint4*)lx = x0; *(uint4*)(lx + 8) = x1;
    *(uint4*)lw = w0; *(uint4*)(lw + 8) = w1;
    __syncthreads();
    const u16* ax = &Xl[(wave * 16 + l15) * 72 + quad * 8];
#pragma unroll
    for (int kk = 0; kk < 64; kk += 32) {
      bf16x8 af = *(const bf16x8*)(ax + kk);
#pragma unroll
      for (int nt = 0; nt < 4; ++nt) {
        bf16x8 bfr = *(const bf16x8*)&Wl[(nt * 16 + l15) * 72 + kk + quad * 8];
        acc[nt] = __builtin_amdgcn_mfma_f32_16x16x32_bf16(af, bfr, acc[nt], 0, 0, 0);
      }
    }
  }
  int row0 = tileM + wave * 16 + quad * 4;
#pragma unroll
  for (int nt = 0; nt < 4; ++nt) {
    int col = tileN + nt * 16 + l15;
    float bv = (bm == 1) ? bias[col] : 0.0f;
#pragma unroll
    for (int r = 0; r < 4; ++r) {
      int row = row0 + r;
      float v = acc[nt][r] + bv;
      if (bm == 2) v += bias[(row / 196) * bstr + col];
      out[(size_t)row * N + col] = f2bf(v);
    }
  }
}

// ---------------- MFMA attention: one block (4 waves) per (b,h) ----------------
__global__ __launch_bounds__(256, 1) void k_attn2(const u16* __restrict__ qkv, u16* __restrict__ o_out) {
  const int b = blockIdx.x >> 3, h = blockIdx.x & 7;
  __shared__ u16 Ks[208 * 72];
  __shared__ u16 Vt[64 * 232];
  __shared__ u16 Ps[4][16 * 232];
  const int tid = threadIdx.x;
  const int wave = tid >> 6, lane = tid & 63, quad = lane >> 4, l15 = lane & 15;
  const size_t base = (size_t)b * 196 * 1536 + (size_t)h * 64;

  for (int i = tid; i < 64 * 232 / 4; i += 256) ((unsigned long long*)Vt)[i] = 0ULL;
  for (int i = tid; i < 4 * 16 * 24; i += 256) {
    int w = i / 384, rem = i - w * 384;
    int r = rem / 24, c = rem - r * 24;
    Ps[w][r * 232 + 208 + c] = 0;
  }
  __syncthreads();

  for (int idx = tid; idx < 208 * 8; idx += 256) {
    int r = idx >> 3, c = (idx & 7) * 8;
    uint4 v = {0, 0, 0, 0};
    if (r < 196) v = *(const uint4*)&qkv[base + 512 + (size_t)r * 1536 + c];
    *(uint4*)&Ks[r * 72 + c] = v;
  }
  for (int idx = tid; idx < 196 * 8; idx += 256) {
    int p = idx >> 3, f0 = (idx & 7) * 8;
    uint4 v = *(const uint4*)&qkv[base + 1024 + (size_t)p * 1536 + f0];
    u16 t[8]; *(uint4*)t = v;
#pragma unroll
    for (int j = 0; j < 8; ++j) Vt[(f0 + j) * 232 + p] = t[j];
  }
  bf16x8 qz = {0, 0, 0, 0, 0, 0, 0, 0};
  bf16x8 qf[4][2];
#pragma unroll
  for (int i = 0; i < 4; ++i) {
    int s = wave + i * 4;
    int row = s * 16 + l15;
#pragma unroll
    for (int c = 0; c < 2; ++c) {
      bf16x8 v = qz;
      if (s < 13 && row < 196)
        v = *(const bf16x8*)&qkv[base + (size_t)row * 1536 + c * 32 + quad * 8];
      qf[i][c] = v;
    }
  }
  __syncthreads();

  const f32x4 z = {0.f, 0.f, 0.f, 0.f};
  for (int i = 0; i < 4; ++i) {
    int s = wave + i * 4;
    if (s >= 13) break;
    f32x4 acc[13];
#pragma unroll
    for (int nt = 0; nt < 13; ++nt) acc[nt] = z;
#pragma unroll
    for (int c = 0; c < 2; ++c) {
      bf16x8 a = qf[i][c];
#pragma unroll
      for (int nt = 0; nt < 13; ++nt) {
        bf16x8 bfr = *(const bf16x8*)&Ks[(nt * 16 + l15) * 72 + c * 32 + quad * 8];
        acc[nt] = __builtin_amdgcn_mfma_f32_16x16x32_bf16(a, bfr, acc[nt], 0, 0, 0);
      }
    }
#pragma unroll
    for (int r = 0; r < 4; ++r) {
      float m = -3e38f;
#pragma unroll
      for (int nt = 0; nt < 13; ++nt) {
        float sv = acc[nt][r] * 0.125f;
        acc[nt][r] = sv;
        if (nt < 12 || l15 < 4) m = fmaxf(m, sv);
      }
#pragma unroll
      for (int off = 1; off < 16; off <<= 1) m = fmaxf(m, __shfl_xor(m, off));
      float ssum = 0.f;
#pragma unroll
      for (int nt = 0; nt < 13; ++nt) {
        float p = (nt < 12 || l15 < 4) ? __expf(acc[nt][r] - m) : 0.f;
        acc[nt][r] = p;
        ssum += p;
      }
#pragma unroll
      for (int off = 1; off < 16; off <<= 1) ssum += __shfl_xor(ssum, off);
      float is = 1.0f / ssum;
      int row = quad * 4 + r;
#pragma unroll
      for (int nt = 0; nt < 13; ++nt) {
        float v = acc[nt][r] * is;
        float vx = __shfl_xor(v, 1);
        if ((l15 & 1) == 0) {
          u32 pk = (u32)f2bf(v) | ((u32)f2bf(vx) << 16);
          *(u32*)&Ps[wave][row * 232 + nt * 16 + l15] = pk;
        }
      }
    }
    f32x4 oacc[4] = {z, z, z, z};
#pragma unroll
    for (int kc = 0; kc < 7; ++kc) {
      bf16x8 a = *(const bf16x8*)&Ps[wave][l15 * 232 + kc * 32 + quad * 8];
#pragma unroll
      for (int nt = 0; nt < 4; ++nt) {
        bf16x8 bfr = *(const bf16x8*)&Vt[(nt * 16 + l15) * 232 + kc * 32 + quad * 8];
        oacc[nt] = __builtin_amdgcn_mfma_f32_16x16x32_bf16(a, bfr, oacc[nt], 0, 0, 0);
      }
    }
#pragma unroll
    for (int nt = 0; nt < 4; ++nt) {
#pragma unroll
      for (int r = 0; r < 4; ++r) {
        int row = s * 16 + quad * 4 + r;
        if (row < 196)
          o_out[((size_t)b * 196 + row) * 512 + h * 64 + nt * 16 + l15] = f2bf(oacc[nt][r]);
      }
    }
  }
}

// ---------------- logits (R3 engine): QL(6272x512) @ KL_b^T, fused row/col max ----------------
// grid (49,32): 128 rows x 208 cols; padded LDS stride 72; loads at loop top.
__global__ __launch_bounds__(256) void k_logits2(const u16* __restrict__ QL, const u16* __restrict__ KL,
                                                 u32* __restrict__ rowmax, u32* __restrict__ colmax) {
  const int row0 = blockIdx.x * 128;
  const int b = blockIdx.y;
  __shared__ u16 Ql[128 * 72];        // 18,432 B
  __shared__ u16 Kl[208 * 72];        // 29,952 B
  __shared__ float colred[2][4 * 208];// 6,656 B
  const int tid = threadIdx.x;
  const int wave = tid >> 6, lane = tid & 63, quad = lane >> 4, l15 = lane & 15;
  const int a0 = row0 / 196;
  const int lsplit = (a0 + 1) * 196 - row0; // >=128 => single a-segment
  const f32x4 z = {0.f, 0.f, 0.f, 0.f};
  f32x4 acc[2][13];
#pragma unroll
  for (int s = 0; s < 2; ++s)
#pragma unroll
    for (int nt = 0; nt < 13; ++nt) acc[s][nt] = z;
  const u16* qbase = QL + (size_t)row0 * 512;
  const u16* kbase = KL + (size_t)b * 196 * 512;

  for (int kc = 0; kc < 512; kc += 64) {
    uint4 qreg[4];
#pragma unroll
    for (int i = 0; i < 4; ++i) {
      int idx = tid + i * 256, r = idx >> 3, c = (idx & 7) * 8;
      qreg[i] = *(const uint4*)(qbase + (size_t)r * 512 + kc + c);
    }
    uint4 kreg[7];
#pragma unroll
    for (int i = 0; i < 7; ++i) {
      int idx = tid + i * 256, r = idx >> 3, c = (idx & 7) * 8;
      uint4 v = {0, 0, 0, 0};
      if (idx < 1664 && r < 196) v = *(const uint4*)(kbase + (size_t)r * 512 + kc + c);
      kreg[i] = v;
    }
    __syncthreads();
#pragma unroll
    for (int i = 0; i < 4; ++i) {
      int idx = tid + i * 256, r = idx >> 3, c = (idx & 7) * 8;
      *(uint4*)&Ql[r * 72 + c] = qreg[i];
    }
#pragma unroll
    for (int i = 0; i < 7; ++i) {
      int idx = tid + i * 256;
      if (idx < 1664) {
        int r = idx >> 3, c = (idx & 7) * 8;
        *(uint4*)&Kl[r * 72 + c] = kreg[i];
      }
    }
    __syncthreads();
#pragma unroll
    for (int kk = 0; kk < 64; kk += 32) {
      bf16x8 af0 = *(const bf16x8*)&Ql[(wave * 16 + l15) * 72 + kk + quad * 8];
      bf16x8 af1 = *(const bf16x8*)&Ql[((wave + 4) * 16 + l15) * 72 + kk + quad * 8];
#pragma unroll
      for (int nt = 0; nt < 13; ++nt) {
        bf16x8 bfr = *(const bf16x8*)&Kl[(nt * 16 + l15) * 72 + kk + quad * 8];
        acc[0][nt] = __builtin_amdgcn_mfma_f32_16x16x32_bf16(af0, bfr, acc[0][nt], 0, 0, 0);
        acc[1][nt] = __builtin_amdgcn_mfma_f32_16x16x32_bf16(af1, bfr, acc[1][nt], 0, 0, 0);
      }
    }
  }
  // ---- rowmax (masked cols >=196; keyed atomic per row) ----
#pragma unroll
  for (int s = 0; s < 2; ++s) {
#pragma unroll
    for (int r = 0; r < 4; ++r) {
      float m = -3e38f;
#pragma unroll
      for (int nt = 0; nt < 13; ++nt)
        if (nt < 12 || l15 < 4) m = fmaxf(m, acc[s][nt][r]);
#pragma unroll
      for (int off = 8; off > 0; off >>= 1) m = fmaxf(m, __shfl_xor(m, off, 16));
      if (l15 == 0) {
        int lr = (wave + s * 4) * 16 + quad * 4 + r;
        int aa = a0, ll = row0 - a0 * 196 + lr;
        if (ll >= 196) { aa += 1; ll -= 196; }
        atomicMax(&rowmax[((size_t)aa * 32 + b) * 196 + ll], encf(m));
      }
    }
  }
  // ---- colmax: segment rows by a before cross-quad shuffles ----
#pragma unroll
  for (int nt = 0; nt < 13; ++nt) {
    float cm0 = -3e38f, cm1 = -3e38f;
#pragma unroll
    for (int s = 0; s < 2; ++s)
#pragma unroll
      for (int r = 0; r < 4; ++r) {
        int lr = (wave + s * 4) * 16 + quad * 4 + r;
        float v = acc[s][nt][r];
        if (lr < lsplit) cm0 = fmaxf(cm0, v); else cm1 = fmaxf(cm1, v);
      }
    cm0 = fmaxf(cm0, __shfl_xor(cm0, 16)); cm0 = fmaxf(cm0, __shfl_xor(cm0, 32));
    cm1 = fmaxf(cm1, __shfl_xor(cm1, 16)); cm1 = fmaxf(cm1, __shfl_xor(cm1, 32));
    if (quad == 0) {
      colred[0][wave * 208 + nt * 16 + l15] = cm0;
      colred[1][wave * 208 + nt * 16 + l15] = cm1;
    }
  }
  __syncthreads();
  for (int c = tid; c < 196; c += 256) {
    float m0 = fmaxf(fmaxf(colred[0][c], colred[0][208 + c]), fmaxf(colred[0][416 + c], colred[0][624 + c]));
    atomicMax(&colmax[((size_t)a0 * 32 + b) * 196 + c], encf(m0));
    if (lsplit < 128) {
      float m1 = fmaxf(fmaxf(colred[1][c], colred[1][208 + c]), fmaxf(colred[1][416 + c], colred[1][624 + c]));
      atomicMax(&colmax[((size_t)(a0 + 1) * 32 + b) * 196 + c], encf(m1));
    }
  }
}

// ---------------- final: S matrix + symmetric cross-entropy ----------------
__global__ __launch_bounds__(1024) void k_final(const u32* __restrict__ maxbuf,
                                                const float* __restrict__ logit_scale, float* __restrict__ out) {
  __shared__ float S[1024];
  __shared__ float terms[64];
  int tid = threadIdx.x;
  float sc = 0.5f * __expf(logit_scale[0]);
  const uint4* rp = (const uint4*)(maxbuf + (size_t)tid * 196);
  const uint4* cp = (const uint4*)(maxbuf + 200704 + (size_t)tid * 196);
  float s = 0.f;
#pragma unroll 7
  for (int i = 0; i < 49; ++i) {
    uint4 v = rp[i]; s += decf2(v.x) + decf2(v.y) + decf2(v.z) + decf2(v.w);
    uint4 w = cp[i]; s += decf2(w.x) + decf2(w.y) + decf2(w.z) + decf2(w.w);
  }
  S[tid] = sc * s * (1.0f / 196.0f);
  __syncthreads();
  if (tid < 64) {
    int aa = tid & 31;
    bool rowMode = tid < 32;
    float mx = -3e38f;
    for (int j = 0; j < 32; ++j) {
      float v = rowMode ? S[aa * 32 + j] : S[j * 32 + aa];
      mx = fmaxf(mx, v);
    }
    float se = 0.f;
    for (int j = 0; j < 32; ++j) {
      float v = rowMode ? S[aa * 32 + j] : S[j * 32 + aa];
      se += __expf(v - mx);
    }
    terms[tid] = S[aa * 33] - (mx + logf(se));
  }
  __syncthreads();
  if (tid == 0) {
    float s2 = 0.f;
    for (int i = 0; i < 64; ++i) s2 += terms[i];
    out[0] = -s2 * (1.0f / 64.0f);
  }
}

// ---------------- host ----------------
extern "C" void kernel_launch(void* const* d_in, const int* in_sizes, int n_in,
                              void* d_out, int out_size, void* d_ws, size_t ws_size,
                              hipStream_t stream) {
  const float* bef       = (const float*)d_in[0];
  const float* sent      = (const float*)d_in[1];
  const float* aft       = (const float*)d_in[2];
  const float* masks     = (const float*)d_in[3];
  const float* conv1_w   = (const float*)d_in[4];
  const float* conv1_b   = (const float*)d_in[5];
  const float* in_proj_w = (const float*)d_in[6];
  const float* out_proj_w= (const float*)d_in[7];
  const float* conv2_w   = (const float*)d_in[8];
  const float* conv2_b   = (const float*)d_in[9];
  const float* q_w       = (const float*)d_in[10];
  const float* q_b       = (const float*)d_in[11];
  const float* k_w       = (const float*)d_in[12];
  const float* k_b       = (const float*)d_in[13];
  const float* logit_scale = (const float*)d_in[14];
  float* out = (float*)d_out;

  char* ws = (char*)d_ws;
  size_t off = 0;
  auto alloc = [&](size_t bytes) -> char* {
    char* p = ws + off;
    off += (bytes + 255) & ~(size_t)255;
    return p;
  };
  const size_t MROWS = 32 * 196; // 6272
  u16* bef16    = (u16*)alloc(MROWS * 512 * 2);
  u16* aft16    = (u16*)alloc(MROWS * 512 * 2);
  u16* inproj16 = (u16*)alloc(1536 * 512 * 2);
  u16* kw16     = (u16*)alloc(512 * 512 * 2);
  u16* qw16     = (u16*)alloc(512 * 512 * 2);
  u16* wcT16    = (u16*)alloc(512 * 512 * 2);
  u16* woT16    = (u16*)alloc(512 * 512 * 2);
  u16* w1aT16   = (u16*)alloc(512 * 512 * 2);
  u16* wt16     = (u16*)alloc(512 * 512 * 2);
  u16* wcomb16  = (u16*)alloc(512 * 512 * 2);
  u16* weff16   = (u16*)alloc(1536 * 512 * 2);
  float* biasq  = (float*)alloc(512 * 4);
  float* biasqkv= (float*)alloc(32 * 1536 * 4);
  u16* qkv16    = (u16*)alloc(MROWS * 1536 * 2);
  u16* oattn16  = (u16*)alloc(MROWS * 512 * 2);
  u16* QL16     = (u16*)alloc(MROWS * 512 * 2);
  u16* KL16     = (u16*)alloc(MROWS * 512 * 2);
  u32* maxbuf   = (u32*)alloc(2 * 32 * 32 * 196 * 4); // rowmax | colmax
  u32* rowmax   = maxbuf;
  u32* colmax   = maxbuf + 32 * 32 * 196;

  // casts + maxbuf zero (1,067,008 items = 4168 blocks exactly)
  k_prep<<<4168, 256, 0, stream>>>(bef, aft, in_proj_w, k_w, q_w,
                                   bef16, aft16, inproj16, kw16, qw16, (uint4*)maxbuf);
  k_transpose3<<<dim3(16, 16, 3), 256, 0, stream>>>(conv2_w, wcT16, out_proj_w, woT16, conv1_w, w1aT16);
  k_sentbias3<<<33, 256, 0, stream>>>(sent, masks, conv1_w, conv1_b, in_proj_w,
                                      q_w, conv2_b, q_b, biasqkv, biasq);
  // merged: y<8 -> Wt = Wq @ Wc (512x512, x<8) ; y>=8 -> Weff = Winproj @ W1a (1536x512)
  k_gemm<<<dim3(24, 16), 256, 0, stream>>>(qw16, wcT16, wt16, nullptr, 512, 0, 0, 8,
                                           inproj16, w1aT16, weff16, nullptr, 512, 0, 0, 8);
  // Wcomb = Wt @ Wo (512x512)
  k_gemm<<<dim3(8, 8), 256, 0, stream>>>(wt16, woT16, wcomb16, nullptr, 512, 0, 0, 8,
                                         wt16, woT16, wcomb16, nullptr, 512, 0, 0, 99);
  // qkv = bef @ Weff^T + biasqkv[b]  (v1 folded away)
  k_gemm<<<dim3(98, 24), 256, 0, stream>>>(bef16, weff16, qkv16, biasqkv, 1536, 2, 1536, 98,
                                           bef16, weff16, qkv16, biasqkv, 1536, 2, 1536, 99);
  // attention (MFMA)
  k_attn2<<<256, 256, 0, stream>>>(qkv16, oattn16);
  // merged: y<8 -> QL = o_attn @ Wcomb^T + biasq ; y>=8 -> KL = aft @ k_w^T + k_b
  k_gemm<<<dim3(98, 16), 256, 0, stream>>>(oattn16, wcomb16, QL16, biasq, 512, 1, 0, 98,
                                           aft16, kw16, KL16, k_b, 512, 1, 0, 8);
  // logits reductions
  k_logits2<<<dim3(49, 32), 256, 0, stream>>>(QL16, KL16, rowmax, colmax);
  // final loss
  k_final<<<1, 1024, 0, stream>>>(maxbuf, logit_scale, out);
}